// Round 16
// baseline (641.545 us; speedup 1.0000x reference)
//
#include <hip/hip_runtime.h>
#include <math.h>
#include <stdint.h>

// Problem constants
#define M_TOK 32768   // B*S
#define D_IN  1024
#define F_HID 2048
#define E_EXP 64

#define O_ORI 0
#define O_RTR (M_TOK * E_EXP)
#define O_IDX (2 * M_TOK * E_EXP)

typedef _Float16 half8 __attribute__((ext_vector_type(8)));
typedef float    f32x4 __attribute__((ext_vector_type(4)));
typedef unsigned int uint32;
typedef uint32   u32x4 __attribute__((ext_vector_type(4)));

// ---- workspace layout (bytes) ----
#define WS_XH  ((size_t)0)
#define WS_XL  (WS_XH  + (size_t)M_TOK * D_IN * 2)
#define WS_W1H (WS_XL  + (size_t)M_TOK * D_IN * 2)
#define WS_W1L (WS_W1H + (size_t)D_IN * F_HID * 2)
#define WS_W2H (WS_W1L + (size_t)D_IN * F_HID * 2)
#define WS_W2L (WS_W2H + (size_t)F_HID * E_EXP * 2)
#define WS_NEED (WS_W2L + (size_t)F_HID * E_EXP * 2)

// Split with baked scale: plane1 = sc*hi(v) (exact), plane2 = sc*(v - hi(v))
__device__ __forceinline__ void split_sc(float v, float sc, unsigned short& h, unsigned short& l) {
    const _Float16 hh = (_Float16)v;
    const float hf = (float)hh;
    const _Float16 hs = (_Float16)(hf * sc);          // exact (power-of-2 scale)
    const _Float16 ls = (_Float16)((v - hf) * sc);
    h = __builtin_bit_cast(unsigned short, hs);
    l = __builtin_bit_cast(unsigned short, ls);
}

// ============ fused prep kernel ============
// x, W1 planes: scale 64  (products => 4096 * true value, single accumulator)
// W2 planes:    scale 16  (h planes also 16 => 256 * logit)
#define NB_X  (M_TOK * D_IN / 4 / 256)     // 32768
#define NB_W1 ((D_IN / 32) * (F_HID / 32)) // 2048
#define NB_W2 (F_HID / 32)                 // 64

__global__ void prep_all(const float* __restrict__ x,
                         const float* __restrict__ W1,
                         const float* __restrict__ W2,
                         unsigned short* __restrict__ xh, unsigned short* __restrict__ xl,
                         unsigned short* __restrict__ w1h, unsigned short* __restrict__ w1l,
                         unsigned short* __restrict__ w2h, unsigned short* __restrict__ w2l)
{
    const int b = blockIdx.x;
    if (b < NB_X) {
        size_t i = ((size_t)b * 256 + threadIdx.x) * 4;
        const float4 v = *(const float4*)&x[i];
        ushort4 h, l;
        split_sc(v.x, 64.f, h.x, l.x); split_sc(v.y, 64.f, h.y, l.y);
        split_sc(v.z, 64.f, h.z, l.z); split_sc(v.w, 64.f, h.w, l.w);
        *(ushort4*)&xh[i] = h;
        *(ushort4*)&xl[i] = l;
    } else if (b < NB_X + NB_W1) {
        __shared__ float t[32][33];
        const int bb = b - NB_X;
        const int d0 = (bb & 31) * 32;
        const int f0 = (bb >> 5) * 32;
        const int r  = threadIdx.x >> 3;
        const int c4 = (threadIdx.x & 7) * 4;
        const float4 v = *(const float4*)&W1[(size_t)(d0 + r) * F_HID + f0 + c4];
        t[r][c4 + 0] = v.x; t[r][c4 + 1] = v.y; t[r][c4 + 2] = v.z; t[r][c4 + 3] = v.w;
        __syncthreads();
        ushort4 h, l;
        split_sc(t[c4 + 0][r], 64.f, h.x, l.x);
        split_sc(t[c4 + 1][r], 64.f, h.y, l.y);
        split_sc(t[c4 + 2][r], 64.f, h.z, l.z);
        split_sc(t[c4 + 3][r], 64.f, h.w, l.w);
        *(ushort4*)&w1h[(size_t)(f0 + r) * D_IN + d0 + c4] = h;
        *(ushort4*)&w1l[(size_t)(f0 + r) * D_IN + d0 + c4] = l;
    } else {
        const int s  = b - NB_X - NB_W1;    // 0..63
        const int nt = threadIdx.x >> 6;    // 0..3
        const int l  = threadIdx.x & 63;
        const int fb = s * 32 + (l >> 4) * 8;
        const int e  = nt * 16 + (l & 15);
        unsigned short h[8], lo[8];
#pragma unroll
        for (int j = 0; j < 8; ++j)
            split_sc(W2[(size_t)(fb + j) * E_EXP + e], 16.f, h[j], lo[j]);
        const size_t base = ((size_t)(s * 4 + nt) * 64 + l) * 8;
        ((ushort4*)&w2h[base])[0] = make_ushort4(h[0], h[1], h[2], h[3]);
        ((ushort4*)&w2h[base])[1] = make_ushort4(h[4], h[5], h[6], h[7]);
        ((ushort4*)&w2l[base])[0] = make_ushort4(lo[0], lo[1], lo[2], lo[3]);
        ((ushort4*)&w2l[base])[1] = make_ushort4(lo[4], lo[5], lo[6], lo[7]);
    }
}

// ============ common helpers ============

__device__ __forceinline__ uint32 swz(uint32 o) { return o ^ (((o >> 7) & 7u) << 4); }

#define STAGE16(SRCP, DSTP) \
    __builtin_amdgcn_global_load_lds((const __attribute__((address_space(1))) void*)(SRCP), \
                                     (__attribute__((address_space(3))) void*)(DSTP), 16, 0, 0)

// ============ kernel A: fully-fused router, minimal-sync K-loop (r15 + polish).
// Grid 256 (1 block/CU), block 512. Each block: 128 tokens x full F (8 chunks of 256 f).
// 3-buffer LDS rotation (distance-2 prefetch) => stage target (t+2)%3 is WAR-free under a
// SINGLE top-of-step barrier. Per step: {vmcnt(6); s_barrier; stage t+2 (earliest issue);
// read 16 frags; setprio(1)+48 MFMA}. #pragma unroll 3 makes buffer indices compile-time.
// Then h-pack + GEMM2 + in-kernel epilogue (r15-verbatim). ============

#define A_BUF(b)  ((b) * 16384)            // 3 x 16 KB (hi@0, lo@+8192)
#define B_BUF(b)  (49152 + (b) * 32768)    // 3 x 32 KB (hi@0, lo@+16384)

__launch_bounds__(512, 2)
__global__ void router_one(const unsigned short* __restrict__ xh, const unsigned short* __restrict__ xl,
                           const unsigned short* __restrict__ w1h, const unsigned short* __restrict__ w1l,
                           const unsigned short* __restrict__ w2fh, const unsigned short* __restrict__ w2fl,
                           const float* __restrict__ b1, const float* __restrict__ b2,
                           float* __restrict__ out)
{
    // Arena 144 KiB: A 3x16K at 0, B 3x32K at 49152. Tail reuses as h-tile [128][256] u32.
    __shared__ __align__(16) unsigned char lds[147456];

    const int tid  = threadIdx.x;
    const int lane = tid & 63;
    const int w    = tid >> 6;         // 0..7
    const int c15  = lane & 15;
    const int g    = lane >> 4;
    const int wr   = w >> 2;           // 0..1 : 64-token half
    const int wc   = w & 3;            // 0..3 : 64-f quarter

    const size_t tok0 = (size_t)blockIdx.x * 128;

    // staging source mapping (both-sides swizzle); A: 1 chunk/thread, B: 2 chunks/thread
    uint32 arow, ahalf, brow[2], bhalf[2];
    {
        const uint32 sA = swz((uint32)(tid * 16));
        arow = sA >> 6; ahalf = (sA & 63u) >> 1;
#pragma unroll
        for (int j = 0; j < 2; ++j) {
            const uint32 sB = swz((uint32)(j * 8192 + w * 1024 + lane * 16));
            brow[j] = sB >> 6; bhalf[j] = (sB & 63u) >> 1;
        }
    }

    // fragment read offsets (loop-invariant, swizzled; 64-B rows)
    uint32 offA[4], offB[4];
#pragma unroll
    for (int m = 0; m < 4; ++m)
        offA[m] = swz((uint32)((wr * 64 + m * 16 + c15) * 64 + g * 16));
#pragma unroll
    for (int n = 0; n < 4; ++n)
        offB[n] = swz((uint32)((wc * 64 + n * 16 + c15) * 64 + g * 16));

    f32x4 acc2[4];                     // full logits: 16 tok x 64 e per wave, over all F
#pragma unroll
    for (int nt = 0; nt < 4; ++nt) acc2[nt] = (f32x4){0.f, 0.f, 0.f, 0.f};

// staging pieces (6 loads/tile total; A=2, Bj0=2, Bj1=2)
#define STAGE_A(T, WB) do {                                                          \
    const int d0_ = (T) * 32;                                                        \
    const size_t asrc = (tok0 + arow) * D_IN + (size_t)(d0_ + (int)ahalf);           \
    STAGE16(xh + asrc, lds + A_BUF(WB) + w * 1024);                                  \
    STAGE16(xl + asrc, lds + A_BUF(WB) + 8192 + w * 1024);                           \
} while (0)
#define STAGE_B(T, WB, F0, J) do {                                                   \
    const int d0_ = (T) * 32;                                                        \
    const size_t bsrc = ((size_t)(F0) + brow[J]) * D_IN + (size_t)(d0_ + (int)bhalf[J]); \
    STAGE16(w1h + bsrc, lds + B_BUF(WB) + (J) * 8192 + w * 1024);                    \
    STAGE16(w1l + bsrc, lds + B_BUF(WB) + 16384 + (J) * 8192 + w * 1024);            \
} while (0)

#pragma unroll 1
    for (int fc = 0; fc < F_HID; fc += 256) {
        f32x4 acc[4][4];
#pragma unroll
        for (int m = 0; m < 4; ++m)
#pragma unroll
            for (int n = 0; n < 4; ++n) acc[m][n] = (f32x4){0.f, 0.f, 0.f, 0.f};

        __syncthreads();               // protect arena from previous chunk's readers
        STAGE_A(0, 0); STAGE_B(0, 0, fc, 0); STAGE_B(0, 0, fc, 1);
        STAGE_A(1, 1); STAGE_B(1, 1, fc, 0); STAGE_B(1, 1, fc, 1);

#pragma unroll 3
        for (int t = 0; t < 32; ++t) {
            // 6 loads/tile; FIFO => vmcnt(6) certifies tile t complete in LDS.
            if (t < 31) asm volatile("s_waitcnt vmcnt(6)" ::: "memory");
            else        asm volatile("s_waitcnt vmcnt(0)" ::: "memory");
            __builtin_amdgcn_s_barrier();   // the ONLY barrier per step
            const int rb = t % 3;           // compile-time under unroll-3
            const int wb = (t + 2) % 3;
            const bool do_stage = (t + 2 < 32);
            const unsigned char* Ab = lds + A_BUF(rb);
            const unsigned char* Bb = lds + B_BUF(rb);

            // issue prefetch of tile t+2 FIRST (WAR-free: its readers finished at step t-1)
            if (do_stage) {
                STAGE_A(t + 2, wb);
                STAGE_B(t + 2, wb, fc, 0);
                STAGE_B(t + 2, wb, fc, 1);
            }

            half8 a1f[4], a2f[4], b1f[4], b2f[4];
#pragma unroll
            for (int m = 0; m < 4; ++m) {
                a1f[m] = *(const half8*)(Ab + offA[m]);
                a2f[m] = *(const half8*)(Ab + 8192 + offA[m]);
            }
#pragma unroll
            for (int n = 0; n < 4; ++n) {
                b1f[n] = *(const half8*)(Bb + offB[n]);
                b2f[n] = *(const half8*)(Bb + 16384 + offB[n]);
            }
            __builtin_amdgcn_s_setprio(1);
#pragma unroll
            for (int m = 0; m < 4; ++m)
#pragma unroll
                for (int n = 0; n < 4; ++n) {
                    acc[m][n] = __builtin_amdgcn_mfma_f32_16x16x32_f16(a1f[m], b1f[n], acc[m][n], 0, 0, 0);
                    acc[m][n] = __builtin_amdgcn_mfma_f32_16x16x32_f16(a1f[m], b2f[n], acc[m][n], 0, 0, 0);
                    acc[m][n] = __builtin_amdgcn_mfma_f32_16x16x32_f16(a2f[m], b1f[n], acc[m][n], 0, 0, 0);
                }
            __builtin_amdgcn_s_setprio(0);
        }

        // ---- tail: pack h (relu + fp16 split, scale 16) into h-tile ----
        __syncthreads();               // all K-loop LDS reads consumed; arena becomes h-tile
        {
            float bv[4];
#pragma unroll
            for (int n = 0; n < 4; ++n) bv[n] = b1[fc + wc * 64 + n * 16 + c15];
#pragma unroll
            for (int m = 0; m < 4; ++m)
#pragma unroll
                for (int n = 0; n < 4; ++n)
#pragma unroll
                    for (int r = 0; r < 4; ++r) {
                        float hv = acc[m][n][r] * (1.f / 4096.f) + bv[n];
                        hv = fmaxf(hv, 0.f);
                        const _Float16 hh = (_Float16)hv;
                        const float hf = (float)hh;
                        const _Float16 hsv = (_Float16)(hf * 16.f);
                        const _Float16 lsv = (_Float16)((hv - hf) * 16.f);
                        const uint32 pk = (uint32)__builtin_bit_cast(unsigned short, hsv)
                                        | ((uint32)__builtin_bit_cast(unsigned short, lsv) << 16);
                        const int tok = wr * 64 + m * 16 + g * 4 + r;
                        const int fl  = wc * 64 + n * 16 + c15;
                        *(uint32*)(lds + tok * 1024 + ((fl * 4) ^ ((tok & 15) << 4))) = pk;
                    }
        }
        __syncthreads();

        // ---- GEMM2 over this chunk: 16 tok x 64 e per wave, accumulate acc2 ----
        {
            const int tokA = w * 16 + c15;
#pragma unroll
            for (int s = 0; s < 8; ++s) {
                const int kf = s * 32 + g * 8;
                const int sg = (fc >> 5) + s;
                half8 bf1[4], bf2[4];
#pragma unroll
                for (int nt = 0; nt < 4; ++nt) {
                    const size_t base = ((size_t)(sg * 4 + nt) * 64 + lane) * 8;
                    bf1[nt] = *(const half8*)&w2fh[base];
                    bf2[nt] = *(const half8*)&w2fl[base];
                }
                const u32x4 q0 = *(const u32x4*)(lds + tokA * 1024 + (((kf    ) * 4) ^ (c15 << 4)));
                const u32x4 q1 = *(const u32x4*)(lds + tokA * 1024 + (((kf + 4) * 4) ^ (c15 << 4)));
                u32x4 hi4, lo4;
                hi4[0] = __builtin_amdgcn_perm(q0[1], q0[0], 0x05040100u);
                hi4[1] = __builtin_amdgcn_perm(q0[3], q0[2], 0x05040100u);
                hi4[2] = __builtin_amdgcn_perm(q1[1], q1[0], 0x05040100u);
                hi4[3] = __builtin_amdgcn_perm(q1[3], q1[2], 0x05040100u);
                lo4[0] = __builtin_amdgcn_perm(q0[1], q0[0], 0x07060302u);
                lo4[1] = __builtin_amdgcn_perm(q0[3], q0[2], 0x07060302u);
                lo4[2] = __builtin_amdgcn_perm(q1[1], q1[0], 0x07060302u);
                lo4[3] = __builtin_amdgcn_perm(q1[3], q1[2], 0x07060302u);
                const half8 a1 = __builtin_bit_cast(half8, hi4);
                const half8 a2 = __builtin_bit_cast(half8, lo4);
#pragma unroll
                for (int nt = 0; nt < 4; ++nt) {
                    acc2[nt] = __builtin_amdgcn_mfma_f32_16x16x32_f16(a1, bf1[nt], acc2[nt], 0, 0, 0);
                    acc2[nt] = __builtin_amdgcn_mfma_f32_16x16x32_f16(a1, bf2[nt], acc2[nt], 0, 0, 0);
                    acc2[nt] = __builtin_amdgcn_mfma_f32_16x16x32_f16(a2, bf1[nt], acc2[nt], 0, 0, 0);
                }
            }
        }
        // top-of-loop __syncthreads() orders next chunk's staging after these reads
    }
#undef STAGE_A
#undef STAGE_B

    // ================= in-kernel epilogue =================
    __syncthreads();                   // all GEMM2 reads done; arena becomes ls[128][68]
    float* ls = (float*)lds;
#pragma unroll
    for (int nt = 0; nt < 4; ++nt)
#pragma unroll
        for (int r = 0; r < 4; ++r) {
            const int tl = w * 16 + g * 4 + r;
            ls[tl * 68 + nt * 16 + c15] = acc2[nt][r] * (1.f / 256.f);
        }
    __syncthreads();

    const int e = lane;
    const float be = b2[e];
#pragma unroll 1
    for (int i = 0; i < 16; ++i) {
        const float l = ls[(w * 16 + i) * 68 + e] + be;

        // top-1 (ties -> lower index)
        float v = l; int idx = e;
#pragma unroll
        for (int m = 32; m >= 1; m >>= 1) {
            const float ov = __shfl_xor(v, m, 64);
            const int   oi = __shfl_xor(idx, m, 64);
            if (ov > v || (ov == v && oi < idx)) { v = ov; idx = oi; }
        }
        const float m1 = v; const int i1 = idx;

        // top-2
        v = (e == i1) ? -INFINITY : l; idx = e;
#pragma unroll
        for (int m = 32; m >= 1; m >>= 1) {
            const float ov = __shfl_xor(v, m, 64);
            const int   oi = __shfl_xor(idx, m, 64);
            if (ov > v || (ov == v && oi < idx)) { v = ov; idx = oi; }
        }
        const int i2 = idx;

        const float ex = expf((l - m1) * 100.0f);
        float s = ex;
#pragma unroll
        for (int m = 32; m >= 1; m >>= 1) s += __shfl_xor(s, m, 64);
        const float ori = ex / s;

        const float q = (e == i1 || e == i2) ? expf(l - m1) : 0.f;
        float s2 = q;
#pragma unroll
        for (int m = 32; m >= 1; m >>= 1) s2 += __shfl_xor(s2, m, 64);
        const float rtr = q / s2;

        const size_t tok = tok0 + (size_t)w * 16 + i;
        out[O_ORI + tok * E_EXP + e] = ori;
        out[O_RTR + tok * E_EXP + e] = rtr;
        if (e == 0) {
            out[O_IDX + tok * 2 + 0] = (float)i1;
            out[O_IDX + tok * 2 + 1] = (float)i2;
        }
    }
}

// ============ fallback: round-3 fused kernel (known-good; frag-major W2) ============

#define BT  64
#define NB  256

__launch_bounds__(256, 2)
__global__ void router_mfma(const unsigned short* __restrict__ xh, const unsigned short* __restrict__ xl,
                            const unsigned short* __restrict__ w1h, const unsigned short* __restrict__ w1l,
                            const unsigned short* __restrict__ w2fh, const unsigned short* __restrict__ w2fl,
                            const float* __restrict__ b1, const float* __restrict__ b2,
                            float* __restrict__ out)
{
    __shared__ __align__(16) unsigned char xs_h[BT * 64];
    __shared__ __align__(16) unsigned char xs_l[BT * 64];
    __shared__ __align__(16) unsigned char w1s_h[NB * 64];
    __shared__ __align__(16) unsigned char w1s_l[NB * 64];
    __shared__ __align__(16) unsigned char hsbuf[BT * 132 * 4];

    const int tid  = threadIdx.x;
    const int lane = tid & 63;
    const int w    = tid >> 6;
    const int c15  = lane & 15;
    const int g    = lane >> 4;
    const size_t tok0 = (size_t)blockIdx.x * BT;

    uint32* hs = (uint32*)hsbuf;
    float*  ls = (float*)hsbuf;

    f32x4 acc2h[4], acc2x[4];
#pragma unroll
    for (int nt = 0; nt < 4; ++nt) {
        acc2h[nt] = (f32x4){0.f, 0.f, 0.f, 0.f};
        acc2x[nt] = (f32x4){0.f, 0.f, 0.f, 0.f};
    }

    const uint32 kqb = (uint32)g * 16u;

    for (int fc = 0; fc < F_HID; fc += NB) {
        f32x4 ahh[4][4], axx[4][4];
#pragma unroll
        for (int mt = 0; mt < 4; ++mt)
#pragma unroll
            for (int nt = 0; nt < 4; ++nt) {
                ahh[mt][nt] = (f32x4){0.f, 0.f, 0.f, 0.f};
                axx[mt][nt] = (f32x4){0.f, 0.f, 0.f, 0.f};
            }

        for (int d0 = 0; d0 < D_IN; d0 += 32) {
            __syncthreads();
            {
                uint32 o = (uint32)w * 1024u + (uint32)lane * 16u;
                uint32 s = swz(o);
                uint32 r = s >> 6, hb = (s & 63u) >> 1;
                const unsigned short* sp;
                sp = xh + (tok0 + r) * D_IN + (size_t)(d0 + (int)hb);
                STAGE16(sp, xs_h + (size_t)w * 1024);
                sp = xl + (tok0 + r) * D_IN + (size_t)(d0 + (int)hb);
                STAGE16(sp, xs_l + (size_t)w * 1024);
#pragma unroll
                for (int q = 0; q < 4; ++q) {
                    const uint32 c_ = (uint32)(q * 4 + w);
                    uint32 o2 = c_ * 1024u + (uint32)lane * 16u;
                    uint32 s2 = swz(o2);
                    uint32 r2 = s2 >> 6, hb2 = (s2 & 63u) >> 1;
                    sp = w1h + ((size_t)(fc + (int)r2)) * D_IN + (size_t)(d0 + (int)hb2);
                    STAGE16(sp, w1s_h + (size_t)c_ * 1024);
                    sp = w1l + ((size_t)(fc + (int)r2)) * D_IN + (size_t)(d0 + (int)hb2);
                    STAGE16(sp, w1s_l + (size_t)c_ * 1024);
                }
            }
            __syncthreads();

            half8 ah[4], al[4], bh[4], bl[4];
#pragma unroll
            for (int mt = 0; mt < 4; ++mt) {
                const uint32 off = swz((uint32)(mt * 16 + c15) * 64u + kqb);
                ah[mt] = *(const half8*)(xs_h + off);
                al[mt] = *(const half8*)(xs_l + off);
            }
#pragma unroll
            for (int nt = 0; nt < 4; ++nt) {
                const uint32 row = (uint32)(w * 64 + nt * 16 + c15);
                const uint32 off = swz(row * 64u + kqb);
                bh[nt] = *(const half8*)(w1s_h + off);
                bl[nt] = *(const half8*)(w1s_l + off);
            }
#pragma unroll
            for (int mt = 0; mt < 4; ++mt)
#pragma unroll
                for (int nt = 0; nt < 4; ++nt) {
                    ahh[mt][nt] = __builtin_amdgcn_mfma_f32_16x16x32_f16(ah[mt], bh[nt], ahh[mt][nt], 0, 0, 0);
                    axx[mt][nt] = __builtin_amdgcn_mfma_f32_16x16x32_f16(ah[mt], bl[nt], axx[mt][nt], 0, 0, 0);
                    axx[mt][nt] = __builtin_amdgcn_mfma_f32_16x16x32_f16(al[mt], bh[nt], axx[mt][nt], 0, 0, 0);
                }
        }

        const int fl0 = (w & 1) * 64;
#pragma unroll
        for (int phase = 0; phase < 2; ++phase) {
            if ((w >> 1) == phase) {
#pragma unroll
                for (int nt = 0; nt < 4; ++nt) {
                    const float b1v = b1[fc + w * 64 + nt * 16 + c15];
#pragma unroll
                    for (int mt = 0; mt < 4; ++mt) {
#pragma unroll
                        for (int r = 0; r < 4; ++r) {
                            float hv = (ahh[mt][nt][r] + axx[mt][nt][r]) * (1.f / 4096.f) + b1v;
                            hv = fmaxf(hv, 0.f);
                            const _Float16 hhv0 = (_Float16)hv;
                            const float hf = (float)hhv0;
                            const _Float16 hhv = (_Float16)(hf * 16.f);
                            const _Float16 hlv = (_Float16)((hv - hf) * 16.f);
                            uint32 pk = (uint32)__builtin_bit_cast(unsigned short, hhv)
                                      | ((uint32)__builtin_bit_cast(unsigned short, hlv) << 16);
                            const int t = mt * 16 + g * 4 + r;
                            hs[t * 132 + fl0 + nt * 16 + c15] = pk;
                        }
                    }
                }
            }
            __syncthreads();
            const int tA = w * 16 + c15;
#pragma unroll
            for (int ktl = 0; ktl < 4; ++ktl) {
                const u32x4 q0 = *(const u32x4*)&hs[tA * 132 + ktl * 32 + g * 8];
                const u32x4 q1 = *(const u32x4*)&hs[tA * 132 + ktl * 32 + g * 8 + 4];
                u32x4 hi4, lo4;
                hi4[0] = __builtin_amdgcn_perm(q0[1], q0[0], 0x05040100u);
                hi4[1] = __builtin_amdgcn_perm(q0[3], q0[2], 0x05040100u);
                hi4[2] = __builtin_amdgcn_perm(q1[1], q1[0], 0x05040100u);
                hi4[3] = __builtin_amdgcn_perm(q1[3], q1[2], 0x05040100u);
                lo4[0] = __builtin_amdgcn_perm(q0[1], q0[0], 0x07060302u);
                lo4[1] = __builtin_amdgcn_perm(q0[3], q0[2], 0x07060302u);
                lo4[2] = __builtin_amdgcn_perm(q1[1], q1[0], 0x07060302u);
                lo4[3] = __builtin_amdgcn_perm(q1[3], q1[2], 0x07060302u);
                const half8 a_h = __builtin_bit_cast(half8, hi4);
                const half8 a_l = __builtin_bit_cast(half8, lo4);
                const int sg = (fc >> 5) + phase * 4 + ktl;
#pragma unroll
                for (int nt = 0; nt < 4; ++nt) {
                    const size_t base = ((size_t)(sg * 4 + nt) * 64 + lane) * 8;
                    const half8 b_h = *(const half8*)&w2fh[base];
                    const half8 b_l = *(const half8*)&w2fl[base];
                    acc2h[nt] = __builtin_amdgcn_mfma_f32_16x16x32_f16(a_h, b_h, acc2h[nt], 0, 0, 0);
                    acc2x[nt] = __builtin_amdgcn_mfma_f32_16x16x32_f16(a_h, b_l, acc2x[nt], 0, 0, 0);
                    acc2x[nt] = __builtin_amdgcn_mfma_f32_16x16x32_f16(a_l, b_h, acc2x[nt], 0, 0, 0);
                }
            }
            __syncthreads();
        }
    }

#pragma unroll
    for (int nt = 0; nt < 4; ++nt)
#pragma unroll
        for (int r = 0; r < 4; ++r) {
            const int t = w * 16 + g * 4 + r;
            ls[t * 68 + nt * 16 + c15] = (acc2h[nt][r] + acc2x[nt][r]) * (1.f / 256.f);
        }
    __syncthreads();

    const int e = lane;
    const float be = b2[e];
#pragma unroll 1
    for (int i = 0; i < 16; ++i) {
        const float l = ls[(w * 16 + i) * 68 + e] + be;

        float v = l; int idx = e;
#pragma unroll
        for (int m = 32; m >= 1; m >>= 1) {
            const float ov = __shfl_xor(v, m, 64);
            const int   oi = __shfl_xor(idx, m, 64);
            if (ov > v || (ov == v && oi < idx)) { v = ov; idx = oi; }
        }
        const float m1 = v; const int i1 = idx;

        v = (e == i1) ? -INFINITY : l; idx = e;
#pragma unroll
        for (int m = 32; m >= 1; m >>= 1) {
            const float ov = __shfl_xor(v, m, 64);
            const int   oi = __shfl_xor(idx, m, 64);
            if (ov > v || (ov == v && oi < idx)) { v = ov; idx = oi; }
        }
        const int i2 = idx;

        const float ex = expf((l - m1) * 100.0f);
        float s = ex;
#pragma unroll
        for (int m = 32; m >= 1; m >>= 1) s += __shfl_xor(s, m, 64);
        const float ori = ex / s;

        const float q = (e == i1 || e == i2) ? expf(l - m1) : 0.f;
        float s2 = q;
#pragma unroll
        for (int m = 32; m >= 1; m >>= 1) s2 += __shfl_xor(s2, m, 64);
        const float rtr = q / s2;

        const size_t tok = tok0 + (size_t)w * 16 + i;
        out[O_ORI + tok * E_EXP + e] = ori;
        out[O_RTR + tok * E_EXP + e] = rtr;
        if (e == 0) {
            out[O_IDX + tok * 2 + 0] = (float)i1;
            out[O_IDX + tok * 2 + 1] = (float)i2;
        }
    }
}

// ============ launcher ============

extern "C" void kernel_launch(void* const* d_in, const int* in_sizes, int n_in,
                              void* d_out, int out_size, void* d_ws, size_t ws_size,
                              hipStream_t stream) {
    const float* x  = (const float*)d_in[0];
    const float* W1 = (const float*)d_in[1];
    const float* b1 = (const float*)d_in[2];
    const float* W2 = (const float*)d_in[3];
    const float* b2 = (const float*)d_in[4];
    float* out = (float*)d_out;

    unsigned char* ws = (unsigned char*)d_ws;
    unsigned short* xh  = (unsigned short*)(ws + WS_XH);
    unsigned short* xl  = (unsigned short*)(ws + WS_XL);
    unsigned short* w1h = (unsigned short*)(ws + WS_W1H);
    unsigned short* w1l = (unsigned short*)(ws + WS_W1L);
    unsigned short* w2h = (unsigned short*)(ws + WS_W2H);
    unsigned short* w2l = (unsigned short*)(ws + WS_W2L);

    hipLaunchKernelGGL(prep_all, dim3(NB_X + NB_W1 + NB_W2), dim3(256), 0, stream,
                       x, W1, W2, xh, xl, w1h, w1l, w2h, w2l);

    if (ws_size >= WS_NEED) {
        hipLaunchKernelGGL(router_one, dim3(M_TOK / 128), dim3(512), 0, stream,
                           xh, xl, w1h, w1l, w2h, w2l, b1, b2, out);
    } else {
        hipLaunchKernelGGL(router_mfma, dim3(M_TOK / BT), dim3(256), 0, stream,
                           xh, xl, w1h, w1l, w2h, w2l, b1, b2, out);
    }
}

// Round 17
// 482.440 us; speedup vs baseline: 1.3298x; 1.3298x over previous
//
#include <hip/hip_runtime.h>
#include <math.h>
#include <stdint.h>

// Problem constants
#define M_TOK 32768   // B*S
#define D_IN  1024
#define F_HID 2048
#define E_EXP 64

#define O_ORI 0
#define O_RTR (M_TOK * E_EXP)
#define O_IDX (2 * M_TOK * E_EXP)

typedef _Float16 half8 __attribute__((ext_vector_type(8)));
typedef float    f32x4 __attribute__((ext_vector_type(4)));
typedef unsigned int uint32;
typedef uint32   u32x4 __attribute__((ext_vector_type(4)));

// ---- workspace layout (bytes) ----
#define WS_XH  ((size_t)0)
#define WS_XL  (WS_XH  + (size_t)M_TOK * D_IN * 2)
#define WS_W1H (WS_XL  + (size_t)M_TOK * D_IN * 2)
#define WS_W1L (WS_W1H + (size_t)D_IN * F_HID * 2)
#define WS_W2H (WS_W1L + (size_t)D_IN * F_HID * 2)
#define WS_W2L (WS_W2H + (size_t)F_HID * E_EXP * 2)
#define WS_NEED (WS_W2L + (size_t)F_HID * E_EXP * 2)

// Split with baked scale: plane1 = sc*hi(v) (exact), plane2 = sc*(v - hi(v))
__device__ __forceinline__ void split_sc(float v, float sc, unsigned short& h, unsigned short& l) {
    const _Float16 hh = (_Float16)v;
    const float hf = (float)hh;
    const _Float16 hs = (_Float16)(hf * sc);          // exact (power-of-2 scale)
    const _Float16 ls = (_Float16)((v - hf) * sc);
    h = __builtin_bit_cast(unsigned short, hs);
    l = __builtin_bit_cast(unsigned short, ls);
}

// ============ fused prep kernel ============
// x, W1 planes: scale 64  (products => 4096 * true value, single accumulator)
// W2 planes:    scale 16  (h planes also 16 => 256 * logit)
#define NB_X  (M_TOK * D_IN / 4 / 256)     // 32768
#define NB_W1 ((D_IN / 32) * (F_HID / 32)) // 2048
#define NB_W2 (F_HID / 32)                 // 64

__global__ void prep_all(const float* __restrict__ x,
                         const float* __restrict__ W1,
                         const float* __restrict__ W2,
                         unsigned short* __restrict__ xh, unsigned short* __restrict__ xl,
                         unsigned short* __restrict__ w1h, unsigned short* __restrict__ w1l,
                         unsigned short* __restrict__ w2h, unsigned short* __restrict__ w2l)
{
    const int b = blockIdx.x;
    if (b < NB_X) {
        size_t i = ((size_t)b * 256 + threadIdx.x) * 4;
        const float4 v = *(const float4*)&x[i];
        ushort4 h, l;
        split_sc(v.x, 64.f, h.x, l.x); split_sc(v.y, 64.f, h.y, l.y);
        split_sc(v.z, 64.f, h.z, l.z); split_sc(v.w, 64.f, h.w, l.w);
        *(ushort4*)&xh[i] = h;
        *(ushort4*)&xl[i] = l;
    } else if (b < NB_X + NB_W1) {
        __shared__ float t[32][33];
        const int bb = b - NB_X;
        const int d0 = (bb & 31) * 32;
        const int f0 = (bb >> 5) * 32;
        const int r  = threadIdx.x >> 3;
        const int c4 = (threadIdx.x & 7) * 4;
        const float4 v = *(const float4*)&W1[(size_t)(d0 + r) * F_HID + f0 + c4];
        t[r][c4 + 0] = v.x; t[r][c4 + 1] = v.y; t[r][c4 + 2] = v.z; t[r][c4 + 3] = v.w;
        __syncthreads();
        ushort4 h, l;
        split_sc(t[c4 + 0][r], 64.f, h.x, l.x);
        split_sc(t[c4 + 1][r], 64.f, h.y, l.y);
        split_sc(t[c4 + 2][r], 64.f, h.z, l.z);
        split_sc(t[c4 + 3][r], 64.f, h.w, l.w);
        *(ushort4*)&w1h[(size_t)(f0 + r) * D_IN + d0 + c4] = h;
        *(ushort4*)&w1l[(size_t)(f0 + r) * D_IN + d0 + c4] = l;
    } else {
        const int s  = b - NB_X - NB_W1;    // 0..63
        const int nt = threadIdx.x >> 6;    // 0..3
        const int l  = threadIdx.x & 63;
        const int fb = s * 32 + (l >> 4) * 8;
        const int e  = nt * 16 + (l & 15);
        unsigned short h[8], lo[8];
#pragma unroll
        for (int j = 0; j < 8; ++j)
            split_sc(W2[(size_t)(fb + j) * E_EXP + e], 16.f, h[j], lo[j]);
        const size_t base = ((size_t)(s * 4 + nt) * 64 + l) * 8;
        ((ushort4*)&w2h[base])[0] = make_ushort4(h[0], h[1], h[2], h[3]);
        ((ushort4*)&w2h[base])[1] = make_ushort4(h[4], h[5], h[6], h[7]);
        ((ushort4*)&w2l[base])[0] = make_ushort4(lo[0], lo[1], lo[2], lo[3]);
        ((ushort4*)&w2l[base])[1] = make_ushort4(lo[4], lo[5], lo[6], lo[7]);
    }
}

// ============ common helpers ============

__device__ __forceinline__ uint32 swz(uint32 o) { return o ^ (((o >> 7) & 7u) << 4); }

#define STAGE16(SRCP, DSTP) \
    __builtin_amdgcn_global_load_lds((const __attribute__((address_space(1))) void*)(SRCP), \
                                     (__attribute__((address_space(3))) void*)(DSTP), 16, 0, 0)

// ============ kernel A: fully-fused router, minimal-sync K-loop (round-15 verbatim,
// best measured: 483.4 us total, MfmaUtil 44.5%, zero spill).
// Grid 256 (1 block/CU), block 512. Each block: 128 tokens x full F (8 chunks of 256 f).
// 3-buffer LDS rotation (distance-2 prefetch) => stage target (t+2)%3 is WAR-free under a
// SINGLE top-of-step barrier. Per step: {vmcnt(6); s_barrier; read 16 frags; stage t+2;
// setprio(1)+48 MFMA}. Then h-pack + GEMM2 + in-kernel epilogue. ============

#define A_BUF(b)  ((b) * 16384)            // 3 x 16 KB (hi@0, lo@+8192)
#define B_BUF(b)  (49152 + (b) * 32768)    // 3 x 32 KB (hi@0, lo@+16384)

__launch_bounds__(512, 2)
__global__ void router_one(const unsigned short* __restrict__ xh, const unsigned short* __restrict__ xl,
                           const unsigned short* __restrict__ w1h, const unsigned short* __restrict__ w1l,
                           const unsigned short* __restrict__ w2fh, const unsigned short* __restrict__ w2fl,
                           const float* __restrict__ b1, const float* __restrict__ b2,
                           float* __restrict__ out)
{
    // Arena 144 KiB: A 3x16K at 0, B 3x32K at 49152. Tail reuses as h-tile [128][256] u32.
    __shared__ __align__(16) unsigned char lds[147456];

    const int tid  = threadIdx.x;
    const int lane = tid & 63;
    const int w    = tid >> 6;         // 0..7
    const int c15  = lane & 15;
    const int g    = lane >> 4;
    const int wr   = w >> 2;           // 0..1 : 64-token half
    const int wc   = w & 3;            // 0..3 : 64-f quarter

    const size_t tok0 = (size_t)blockIdx.x * 128;

    // staging source mapping (both-sides swizzle); A: 1 chunk/thread, B: 2 chunks/thread
    uint32 arow, ahalf, brow[2], bhalf[2];
    {
        const uint32 sA = swz((uint32)(tid * 16));
        arow = sA >> 6; ahalf = (sA & 63u) >> 1;
#pragma unroll
        for (int j = 0; j < 2; ++j) {
            const uint32 sB = swz((uint32)(j * 8192 + w * 1024 + lane * 16));
            brow[j] = sB >> 6; bhalf[j] = (sB & 63u) >> 1;
        }
    }

    // fragment read offsets (loop-invariant, swizzled; 64-B rows)
    uint32 offA[4], offB[4];
#pragma unroll
    for (int m = 0; m < 4; ++m)
        offA[m] = swz((uint32)((wr * 64 + m * 16 + c15) * 64 + g * 16));
#pragma unroll
    for (int n = 0; n < 4; ++n)
        offB[n] = swz((uint32)((wc * 64 + n * 16 + c15) * 64 + g * 16));

    f32x4 acc2[4];                     // full logits: 16 tok x 64 e per wave, over all F
#pragma unroll
    for (int nt = 0; nt < 4; ++nt) acc2[nt] = (f32x4){0.f, 0.f, 0.f, 0.f};

// staging pieces (6 loads/tile total; A=2, Bj0=2, Bj1=2)
#define STAGE_A(T, WB) do {                                                          \
    const int d0_ = (T) * 32;                                                        \
    const size_t asrc = (tok0 + arow) * D_IN + (size_t)(d0_ + (int)ahalf);           \
    STAGE16(xh + asrc, lds + A_BUF(WB) + w * 1024);                                  \
    STAGE16(xl + asrc, lds + A_BUF(WB) + 8192 + w * 1024);                           \
} while (0)
#define STAGE_B(T, WB, F0, J) do {                                                   \
    const int d0_ = (T) * 32;                                                        \
    const size_t bsrc = ((size_t)(F0) + brow[J]) * D_IN + (size_t)(d0_ + (int)bhalf[J]); \
    STAGE16(w1h + bsrc, lds + B_BUF(WB) + (J) * 8192 + w * 1024);                    \
    STAGE16(w1l + bsrc, lds + B_BUF(WB) + 16384 + (J) * 8192 + w * 1024);            \
} while (0)

#pragma unroll 1
    for (int fc = 0; fc < F_HID; fc += 256) {
        f32x4 acc[4][4];
#pragma unroll
        for (int m = 0; m < 4; ++m)
#pragma unroll
            for (int n = 0; n < 4; ++n) acc[m][n] = (f32x4){0.f, 0.f, 0.f, 0.f};

        __syncthreads();               // protect arena from previous chunk's readers
        STAGE_A(0, 0); STAGE_B(0, 0, fc, 0); STAGE_B(0, 0, fc, 1);
        STAGE_A(1, 1); STAGE_B(1, 1, fc, 0); STAGE_B(1, 1, fc, 1);

#pragma unroll 1
        for (int t = 0; t < 32; ++t) {
            // 6 loads/tile; FIFO => vmcnt(6) certifies tile t complete in LDS.
            if (t < 31) asm volatile("s_waitcnt vmcnt(6)" ::: "memory");
            else        asm volatile("s_waitcnt vmcnt(0)" ::: "memory");
            __builtin_amdgcn_s_barrier();   // the ONLY barrier per step
            const int rb = t % 3;
            const int wb = (t + 2) % 3;
            const bool do_stage = (t + 2 < 32);
            const unsigned char* Ab = lds + A_BUF(rb);
            const unsigned char* Bb = lds + B_BUF(rb);

            half8 a1f[4], a2f[4], b1f[4], b2f[4];
#pragma unroll
            for (int m = 0; m < 4; ++m) {
                a1f[m] = *(const half8*)(Ab + offA[m]);
                a2f[m] = *(const half8*)(Ab + 8192 + offA[m]);
            }
#pragma unroll
            for (int n = 0; n < 4; ++n) {
                b1f[n] = *(const half8*)(Bb + offB[n]);
                b2f[n] = *(const half8*)(Bb + 16384 + offB[n]);
            }
            // prefetch tile t+2 into the WAR-free buffer (readers finished at step t-1)
            if (do_stage) {
                STAGE_A(t + 2, wb);
                STAGE_B(t + 2, wb, fc, 0);
                STAGE_B(t + 2, wb, fc, 1);
            }
            __builtin_amdgcn_s_setprio(1);
#pragma unroll
            for (int m = 0; m < 4; ++m)
#pragma unroll
                for (int n = 0; n < 4; ++n) {
                    acc[m][n] = __builtin_amdgcn_mfma_f32_16x16x32_f16(a1f[m], b1f[n], acc[m][n], 0, 0, 0);
                    acc[m][n] = __builtin_amdgcn_mfma_f32_16x16x32_f16(a1f[m], b2f[n], acc[m][n], 0, 0, 0);
                    acc[m][n] = __builtin_amdgcn_mfma_f32_16x16x32_f16(a2f[m], b1f[n], acc[m][n], 0, 0, 0);
                }
            __builtin_amdgcn_s_setprio(0);
        }

        // ---- tail: pack h (relu + fp16 split, scale 16) into h-tile ----
        __syncthreads();               // all K-loop LDS reads consumed; arena becomes h-tile
        {
            float bv[4];
#pragma unroll
            for (int n = 0; n < 4; ++n) bv[n] = b1[fc + wc * 64 + n * 16 + c15];
#pragma unroll
            for (int m = 0; m < 4; ++m)
#pragma unroll
                for (int n = 0; n < 4; ++n)
#pragma unroll
                    for (int r = 0; r < 4; ++r) {
                        float hv = acc[m][n][r] * (1.f / 4096.f) + bv[n];
                        hv = fmaxf(hv, 0.f);
                        const _Float16 hh = (_Float16)hv;
                        const float hf = (float)hh;
                        const _Float16 hsv = (_Float16)(hf * 16.f);
                        const _Float16 lsv = (_Float16)((hv - hf) * 16.f);
                        const uint32 pk = (uint32)__builtin_bit_cast(unsigned short, hsv)
                                        | ((uint32)__builtin_bit_cast(unsigned short, lsv) << 16);
                        const int tok = wr * 64 + m * 16 + g * 4 + r;
                        const int fl  = wc * 64 + n * 16 + c15;
                        *(uint32*)(lds + tok * 1024 + ((fl * 4) ^ ((tok & 15) << 4))) = pk;
                    }
        }
        __syncthreads();

        // ---- GEMM2 over this chunk: 16 tok x 64 e per wave, accumulate acc2 ----
        {
            const int tokA = w * 16 + c15;
#pragma unroll
            for (int s = 0; s < 8; ++s) {
                const int kf = s * 32 + g * 8;
                const int sg = (fc >> 5) + s;
                half8 bf1[4], bf2[4];
#pragma unroll
                for (int nt = 0; nt < 4; ++nt) {
                    const size_t base = ((size_t)(sg * 4 + nt) * 64 + lane) * 8;
                    bf1[nt] = *(const half8*)&w2fh[base];
                    bf2[nt] = *(const half8*)&w2fl[base];
                }
                const u32x4 q0 = *(const u32x4*)(lds + tokA * 1024 + (((kf    ) * 4) ^ (c15 << 4)));
                const u32x4 q1 = *(const u32x4*)(lds + tokA * 1024 + (((kf + 4) * 4) ^ (c15 << 4)));
                u32x4 hi4, lo4;
                hi4[0] = __builtin_amdgcn_perm(q0[1], q0[0], 0x05040100u);
                hi4[1] = __builtin_amdgcn_perm(q0[3], q0[2], 0x05040100u);
                hi4[2] = __builtin_amdgcn_perm(q1[1], q1[0], 0x05040100u);
                hi4[3] = __builtin_amdgcn_perm(q1[3], q1[2], 0x05040100u);
                lo4[0] = __builtin_amdgcn_perm(q0[1], q0[0], 0x07060302u);
                lo4[1] = __builtin_amdgcn_perm(q0[3], q0[2], 0x07060302u);
                lo4[2] = __builtin_amdgcn_perm(q1[1], q1[0], 0x07060302u);
                lo4[3] = __builtin_amdgcn_perm(q1[3], q1[2], 0x07060302u);
                const half8 a1 = __builtin_bit_cast(half8, hi4);
                const half8 a2 = __builtin_bit_cast(half8, lo4);
#pragma unroll
                for (int nt = 0; nt < 4; ++nt) {
                    acc2[nt] = __builtin_amdgcn_mfma_f32_16x16x32_f16(a1, bf1[nt], acc2[nt], 0, 0, 0);
                    acc2[nt] = __builtin_amdgcn_mfma_f32_16x16x32_f16(a1, bf2[nt], acc2[nt], 0, 0, 0);
                    acc2[nt] = __builtin_amdgcn_mfma_f32_16x16x32_f16(a2, bf1[nt], acc2[nt], 0, 0, 0);
                }
            }
        }
        // top-of-loop __syncthreads() orders next chunk's staging after these reads
    }
#undef STAGE_A
#undef STAGE_B

    // ================= in-kernel epilogue =================
    __syncthreads();                   // all GEMM2 reads done; arena becomes ls[128][68]
    float* ls = (float*)lds;
#pragma unroll
    for (int nt = 0; nt < 4; ++nt)
#pragma unroll
        for (int r = 0; r < 4; ++r) {
            const int tl = w * 16 + g * 4 + r;
            ls[tl * 68 + nt * 16 + c15] = acc2[nt][r] * (1.f / 256.f);
        }
    __syncthreads();

    const int e = lane;
    const float be = b2[e];
#pragma unroll 1
    for (int i = 0; i < 16; ++i) {
        const float l = ls[(w * 16 + i) * 68 + e] + be;

        // top-1 (ties -> lower index)
        float v = l; int idx = e;
#pragma unroll
        for (int m = 32; m >= 1; m >>= 1) {
            const float ov = __shfl_xor(v, m, 64);
            const int   oi = __shfl_xor(idx, m, 64);
            if (ov > v || (ov == v && oi < idx)) { v = ov; idx = oi; }
        }
        const float m1 = v; const int i1 = idx;

        // top-2
        v = (e == i1) ? -INFINITY : l; idx = e;
#pragma unroll
        for (int m = 32; m >= 1; m >>= 1) {
            const float ov = __shfl_xor(v, m, 64);
            const int   oi = __shfl_xor(idx, m, 64);
            if (ov > v || (ov == v && oi < idx)) { v = ov; idx = oi; }
        }
        const int i2 = idx;

        const float ex = expf((l - m1) * 100.0f);
        float s = ex;
#pragma unroll
        for (int m = 32; m >= 1; m >>= 1) s += __shfl_xor(s, m, 64);
        const float ori = ex / s;

        const float q = (e == i1 || e == i2) ? expf(l - m1) : 0.f;
        float s2 = q;
#pragma unroll
        for (int m = 32; m >= 1; m >>= 1) s2 += __shfl_xor(s2, m, 64);
        const float rtr = q / s2;

        const size_t tok = tok0 + (size_t)w * 16 + i;
        out[O_ORI + tok * E_EXP + e] = ori;
        out[O_RTR + tok * E_EXP + e] = rtr;
        if (e == 0) {
            out[O_IDX + tok * 2 + 0] = (float)i1;
            out[O_IDX + tok * 2 + 1] = (float)i2;
        }
    }
}

// ============ fallback: round-3 fused kernel (known-good; frag-major W2) ============

#define BT  64
#define NB  256

__launch_bounds__(256, 2)
__global__ void router_mfma(const unsigned short* __restrict__ xh, const unsigned short* __restrict__ xl,
                            const unsigned short* __restrict__ w1h, const unsigned short* __restrict__ w1l,
                            const unsigned short* __restrict__ w2fh, const unsigned short* __restrict__ w2fl,
                            const float* __restrict__ b1, const float* __restrict__ b2,
                            float* __restrict__ out)
{
    __shared__ __align__(16) unsigned char xs_h[BT * 64];
    __shared__ __align__(16) unsigned char xs_l[BT * 64];
    __shared__ __align__(16) unsigned char w1s_h[NB * 64];
    __shared__ __align__(16) unsigned char w1s_l[NB * 64];
    __shared__ __align__(16) unsigned char hsbuf[BT * 132 * 4];

    const int tid  = threadIdx.x;
    const int lane = tid & 63;
    const int w    = tid >> 6;
    const int c15  = lane & 15;
    const int g    = lane >> 4;
    const size_t tok0 = (size_t)blockIdx.x * BT;

    uint32* hs = (uint32*)hsbuf;
    float*  ls = (float*)hsbuf;

    f32x4 acc2h[4], acc2x[4];
#pragma unroll
    for (int nt = 0; nt < 4; ++nt) {
        acc2h[nt] = (f32x4){0.f, 0.f, 0.f, 0.f};
        acc2x[nt] = (f32x4){0.f, 0.f, 0.f, 0.f};
    }

    const uint32 kqb = (uint32)g * 16u;

    for (int fc = 0; fc < F_HID; fc += NB) {
        f32x4 ahh[4][4], axx[4][4];
#pragma unroll
        for (int mt = 0; mt < 4; ++mt)
#pragma unroll
            for (int nt = 0; nt < 4; ++nt) {
                ahh[mt][nt] = (f32x4){0.f, 0.f, 0.f, 0.f};
                axx[mt][nt] = (f32x4){0.f, 0.f, 0.f, 0.f};
            }

        for (int d0 = 0; d0 < D_IN; d0 += 32) {
            __syncthreads();
            {
                uint32 o = (uint32)w * 1024u + (uint32)lane * 16u;
                uint32 s = swz(o);
                uint32 r = s >> 6, hb = (s & 63u) >> 1;
                const unsigned short* sp;
                sp = xh + (tok0 + r) * D_IN + (size_t)(d0 + (int)hb);
                STAGE16(sp, xs_h + (size_t)w * 1024);
                sp = xl + (tok0 + r) * D_IN + (size_t)(d0 + (int)hb);
                STAGE16(sp, xs_l + (size_t)w * 1024);
#pragma unroll
                for (int q = 0; q < 4; ++q) {
                    const uint32 c_ = (uint32)(q * 4 + w);
                    uint32 o2 = c_ * 1024u + (uint32)lane * 16u;
                    uint32 s2 = swz(o2);
                    uint32 r2 = s2 >> 6, hb2 = (s2 & 63u) >> 1;
                    sp = w1h + ((size_t)(fc + (int)r2)) * D_IN + (size_t)(d0 + (int)hb2);
                    STAGE16(sp, w1s_h + (size_t)c_ * 1024);
                    sp = w1l + ((size_t)(fc + (int)r2)) * D_IN + (size_t)(d0 + (int)hb2);
                    STAGE16(sp, w1s_l + (size_t)c_ * 1024);
                }
            }
            __syncthreads();

            half8 ah[4], al[4], bh[4], bl[4];
#pragma unroll
            for (int mt = 0; mt < 4; ++mt) {
                const uint32 off = swz((uint32)(mt * 16 + c15) * 64u + kqb);
                ah[mt] = *(const half8*)(xs_h + off);
                al[mt] = *(const half8*)(xs_l + off);
            }
#pragma unroll
            for (int nt = 0; nt < 4; ++nt) {
                const uint32 row = (uint32)(w * 64 + nt * 16 + c15);
                const uint32 off = swz(row * 64u + kqb);
                bh[nt] = *(const half8*)(w1s_h + off);
                bl[nt] = *(const half8*)(w1s_l + off);
            }
#pragma unroll
            for (int mt = 0; mt < 4; ++mt)
#pragma unroll
                for (int nt = 0; nt < 4; ++nt) {
                    ahh[mt][nt] = __builtin_amdgcn_mfma_f32_16x16x32_f16(ah[mt], bh[nt], ahh[mt][nt], 0, 0, 0);
                    axx[mt][nt] = __builtin_amdgcn_mfma_f32_16x16x32_f16(ah[mt], bl[nt], axx[mt][nt], 0, 0, 0);
                    axx[mt][nt] = __builtin_amdgcn_mfma_f32_16x16x32_f16(al[mt], bh[nt], axx[mt][nt], 0, 0, 0);
                }
        }

        const int fl0 = (w & 1) * 64;
#pragma unroll
        for (int phase = 0; phase < 2; ++phase) {
            if ((w >> 1) == phase) {
#pragma unroll
                for (int nt = 0; nt < 4; ++nt) {
                    const float b1v = b1[fc + w * 64 + nt * 16 + c15];
#pragma unroll
                    for (int mt = 0; mt < 4; ++mt) {
#pragma unroll
                        for (int r = 0; r < 4; ++r) {
                            float hv = (ahh[mt][nt][r] + axx[mt][nt][r]) * (1.f / 4096.f) + b1v;
                            hv = fmaxf(hv, 0.f);
                            const _Float16 hhv0 = (_Float16)hv;
                            const float hf = (float)hhv0;
                            const _Float16 hhv = (_Float16)(hf * 16.f);
                            const _Float16 hlv = (_Float16)((hv - hf) * 16.f);
                            uint32 pk = (uint32)__builtin_bit_cast(unsigned short, hhv)
                                      | ((uint32)__builtin_bit_cast(unsigned short, hlv) << 16);
                            const int t = mt * 16 + g * 4 + r;
                            hs[t * 132 + fl0 + nt * 16 + c15] = pk;
                        }
                    }
                }
            }
            __syncthreads();
            const int tA = w * 16 + c15;
#pragma unroll
            for (int ktl = 0; ktl < 4; ++ktl) {
                const u32x4 q0 = *(const u32x4*)&hs[tA * 132 + ktl * 32 + g * 8];
                const u32x4 q1 = *(const u32x4*)&hs[tA * 132 + ktl * 32 + g * 8 + 4];
                u32x4 hi4, lo4;
                hi4[0] = __builtin_amdgcn_perm(q0[1], q0[0], 0x05040100u);
                hi4[1] = __builtin_amdgcn_perm(q0[3], q0[2], 0x05040100u);
                hi4[2] = __builtin_amdgcn_perm(q1[1], q1[0], 0x05040100u);
                hi4[3] = __builtin_amdgcn_perm(q1[3], q1[2], 0x05040100u);
                lo4[0] = __builtin_amdgcn_perm(q0[1], q0[0], 0x07060302u);
                lo4[1] = __builtin_amdgcn_perm(q0[3], q0[2], 0x07060302u);
                lo4[2] = __builtin_amdgcn_perm(q1[1], q1[0], 0x07060302u);
                lo4[3] = __builtin_amdgcn_perm(q1[3], q1[2], 0x07060302u);
                const half8 a_h = __builtin_bit_cast(half8, hi4);
                const half8 a_l = __builtin_bit_cast(half8, lo4);
                const int sg = (fc >> 5) + phase * 4 + ktl;
#pragma unroll
                for (int nt = 0; nt < 4; ++nt) {
                    const size_t base = ((size_t)(sg * 4 + nt) * 64 + lane) * 8;
                    const half8 b_h = *(const half8*)&w2fh[base];
                    const half8 b_l = *(const half8*)&w2fl[base];
                    acc2h[nt] = __builtin_amdgcn_mfma_f32_16x16x32_f16(a_h, b_h, acc2h[nt], 0, 0, 0);
                    acc2x[nt] = __builtin_amdgcn_mfma_f32_16x16x32_f16(a_h, b_l, acc2x[nt], 0, 0, 0);
                    acc2x[nt] = __builtin_amdgcn_mfma_f32_16x16x32_f16(a_l, b_h, acc2x[nt], 0, 0, 0);
                }
            }
            __syncthreads();
        }
    }

#pragma unroll
    for (int nt = 0; nt < 4; ++nt)
#pragma unroll
        for (int r = 0; r < 4; ++r) {
            const int t = w * 16 + g * 4 + r;
            ls[t * 68 + nt * 16 + c15] = (acc2h[nt][r] + acc2x[nt][r]) * (1.f / 256.f);
        }
    __syncthreads();

    const int e = lane;
    const float be = b2[e];
#pragma unroll 1
    for (int i = 0; i < 16; ++i) {
        const float l = ls[(w * 16 + i) * 68 + e] + be;

        float v = l; int idx = e;
#pragma unroll
        for (int m = 32; m >= 1; m >>= 1) {
            const float ov = __shfl_xor(v, m, 64);
            const int   oi = __shfl_xor(idx, m, 64);
            if (ov > v || (ov == v && oi < idx)) { v = ov; idx = oi; }
        }
        const float m1 = v; const int i1 = idx;

        v = (e == i1) ? -INFINITY : l; idx = e;
#pragma unroll
        for (int m = 32; m >= 1; m >>= 1) {
            const float ov = __shfl_xor(v, m, 64);
            const int   oi = __shfl_xor(idx, m, 64);
            if (ov > v || (ov == v && oi < idx)) { v = ov; idx = oi; }
        }
        const int i2 = idx;

        const float ex = expf((l - m1) * 100.0f);
        float s = ex;
#pragma unroll
        for (int m = 32; m >= 1; m >>= 1) s += __shfl_xor(s, m, 64);
        const float ori = ex / s;

        const float q = (e == i1 || e == i2) ? expf(l - m1) : 0.f;
        float s2 = q;
#pragma unroll
        for (int m = 32; m >= 1; m >>= 1) s2 += __shfl_xor(s2, m, 64);
        const float rtr = q / s2;

        const size_t tok = tok0 + (size_t)w * 16 + i;
        out[O_ORI + tok * E_EXP + e] = ori;
        out[O_RTR + tok * E_EXP + e] = rtr;
        if (e == 0) {
            out[O_IDX + tok * 2 + 0] = (float)i1;
            out[O_IDX + tok * 2 + 1] = (float)i2;
        }
    }
}

// ============ launcher ============

extern "C" void kernel_launch(void* const* d_in, const int* in_sizes, int n_in,
                              void* d_out, int out_size, void* d_ws, size_t ws_size,
                              hipStream_t stream) {
    const float* x  = (const float*)d_in[0];
    const float* W1 = (const float*)d_in[1];
    const float* b1 = (const float*)d_in[2];
    const float* W2 = (const float*)d_in[3];
    const float* b2 = (const float*)d_in[4];
    float* out = (float*)d_out;

    unsigned char* ws = (unsigned char*)d_ws;
    unsigned short* xh  = (unsigned short*)(ws + WS_XH);
    unsigned short* xl  = (unsigned short*)(ws + WS_XL);
    unsigned short* w1h = (unsigned short*)(ws + WS_W1H);
    unsigned short* w1l = (unsigned short*)(ws + WS_W1L);
    unsigned short* w2h = (unsigned short*)(ws + WS_W2H);
    unsigned short* w2l = (unsigned short*)(ws + WS_W2L);

    hipLaunchKernelGGL(prep_all, dim3(NB_X + NB_W1 + NB_W2), dim3(256), 0, stream,
                       x, W1, W2, xh, xl, w1h, w1l, w2h, w2l);

    if (ws_size >= WS_NEED) {
        hipLaunchKernelGGL(router_one, dim3(M_TOK / 128), dim3(512), 0, stream,
                           xh, xl, w1h, w1l, w2h, w2l, b1, b2, out);
    } else {
        hipLaunchKernelGGL(router_mfma, dim3(M_TOK / BT), dim3(256), 0, stream,
                           xh, xl, w1h, w1l, w2h, w2l, b1, b2, out);
    }
}